// Round 1
// baseline (303.052 us; speedup 1.0000x reference)
//
#include <hip/hip_runtime.h>

#define HW_  (128*240)   // 30720
#define W_   240
#define H_   128
#define B_   4
#define C_   32
#define J_   15
#define TILE 128
#define NTHREADS 256
#define WS_PER_B 21      // [0..8] Kinv, [9..20] T rows 0..2 (3x4 row-major)

__global__ void setup_kernel(const float* __restrict__ K,
                             const float* __restrict__ M,
                             const float* __restrict__ trans,
                             float* __restrict__ ws) {
    int b = threadIdx.x;
    if (b >= B_) return;

    // ---- invert K (3x3), Gauss-Jordan w/ partial pivoting ----
    float a[3][6];
    for (int i = 0; i < 3; i++) {
        for (int j = 0; j < 3; j++) {
            a[i][j]     = K[b * 9 + i * 3 + j];
            a[i][3 + j] = (i == j) ? 1.0f : 0.0f;
        }
    }
    for (int col = 0; col < 3; col++) {
        int piv = col; float mx = fabsf(a[col][col]);
        for (int r = col + 1; r < 3; r++) {
            float v = fabsf(a[r][col]);
            if (v > mx) { mx = v; piv = r; }
        }
        if (piv != col) {
            for (int j = 0; j < 6; j++) { float t = a[col][j]; a[col][j] = a[piv][j]; a[piv][j] = t; }
        }
        float inv = 1.0f / a[col][col];
        for (int j = 0; j < 6; j++) a[col][j] *= inv;
        for (int r = 0; r < 3; r++) {
            if (r == col) continue;
            float f = a[r][col];
            for (int j = 0; j < 6; j++) a[r][j] -= f * a[col][j];
        }
    }
    for (int i = 0; i < 3; i++)
        for (int j = 0; j < 3; j++)
            ws[b * WS_PER_B + i * 3 + j] = a[i][3 + j];

    // ---- invert M (4x4), Gauss-Jordan w/ partial pivoting ----
    float m[4][8];
    for (int i = 0; i < 4; i++) {
        for (int j = 0; j < 4; j++) {
            m[i][j]     = M[b * 16 + i * 4 + j];
            m[i][4 + j] = (i == j) ? 1.0f : 0.0f;
        }
    }
    for (int col = 0; col < 4; col++) {
        int piv = col; float mx = fabsf(m[col][col]);
        for (int r = col + 1; r < 4; r++) {
            float v = fabsf(m[r][col]);
            if (v > mx) { mx = v; piv = r; }
        }
        if (piv != col) {
            for (int j = 0; j < 8; j++) { float t = m[col][j]; m[col][j] = m[piv][j]; m[piv][j] = t; }
        }
        float inv = 1.0f / m[col][col];
        for (int j = 0; j < 8; j++) m[col][j] *= inv;
        for (int r = 0; r < 4; r++) {
            if (r == col) continue;
            float f = m[r][col];
            for (int j = 0; j < 8; j++) m[r][j] -= f * m[col][j];
        }
    }
    // ---- T = trans @ Minv, keep rows 0..2 ----
    for (int i = 0; i < 3; i++) {
        for (int k = 0; k < 4; k++) {
            float s = trans[b * 16 + i * 4 + 0] * m[0][4 + k];
            s += trans[b * 16 + i * 4 + 1] * m[1][4 + k];
            s += trans[b * 16 + i * 4 + 2] * m[2][4 + k];
            s += trans[b * 16 + i * 4 + 3] * m[3][4 + k];
            ws[b * WS_PER_B + 9 + i * 4 + k] = s;
        }
    }
}

__global__ __launch_bounds__(NTHREADS) void points_kernel(
    const float* __restrict__ dep,
    const int*   __restrict__ mask,
    const float* __restrict__ feat,
    const float* __restrict__ diff,
    const float* __restrict__ ws,
    const int*   __restrict__ origW,
    const int*   __restrict__ origH,
    float*       __restrict__ out)
{
    __shared__ __align__(16) float pc_s[TILE * 35];  // flat tile == flat output slice
    __shared__ int m_s[J_ * TILE];

    const int b   = blockIdx.y;
    const int p0  = blockIdx.x * TILE;
    const int tid = threadIdx.x;

    // ---- stage features: pc_s[pl*35 + 3 + c] ----
    const float* fbase = feat + (size_t)b * C_ * HW_ + p0;
    for (int idx = tid; idx < C_ * TILE; idx += NTHREADS) {
        int c  = idx >> 7;          // TILE = 128
        int pl = idx & (TILE - 1);
        pc_s[pl * 35 + 3 + c] = fbase[(size_t)c * HW_ + pl];
    }
    // ---- stage all 15 joint masks ----
    const int* mbase = mask + (size_t)b * HW_ + p0;
    for (int idx = tid; idx < J_ * TILE; idx += NTHREADS) {
        int j  = idx >> 7;
        int pl = idx & (TILE - 1);
        m_s[idx] = mbase[(size_t)j * B_ * HW_ + pl];
    }
    // ---- geometry for the 128 points of this tile ----
    if (tid < TILE) {
        const float* w = ws + b * WS_PER_B;
        const float k00 = w[0], k01 = w[1], k02 = w[2];
        const float k10 = w[3], k11 = w[4], k12 = w[5];
        const float sW = (float)origW[0] / 480.0f;   // 1920/480 = 4.0 exact
        const float sH = (float)origH[0] / (float)H_; // 1080/128 = 8.4375 exact

        int p  = p0 + tid;
        int hh = p / W_;
        int wi = p - hh * W_;
        float x = ((float)wi + 71.0f) * sW;
        float y = (float)hh * sH;

        float x_bak = k00 * x + k01 * y + k02;
        float y_bak = k10 * x + k11 * y + k12;

        const float* d = diff + b * 12;
        float d0 = d[0], d1 = d[1], d2 = d[2], d3 = d[3], d4 = d[4], d5 = d[5];
        float d6 = d[6], d7 = d[7], d8 = d[8], d9 = d[9], d10 = d[10], d11 = d[11];

        float xd = x_bak, yd = y_bak;
        #pragma unroll
        for (int it = 0; it < 5; it++) {
            float r2  = xd * xd + yd * yd;
            float num = 1.0f + ((d7 * r2 + d6) * r2 + d5) * r2;
            float den = 1.0f + ((d4 * r2 + d1) * r2 + d0) * r2;
            float icd = num / den;
            float dX = 2.0f * d2 * xd * yd + d3 * (r2 + 2.0f * xd * xd) + d8 * r2 + d9 * r2 * r2;
            float dY = d2 * (r2 + 2.0f * yd * yd) + 2.0f * d3 * xd * yd + d10 * r2 + d11 * r2 * r2;
            xd = (x_bak - dX) * icd;
            yd = (y_bak - dY) * icd;
        }
        float depth = dep[(size_t)b * HW_ + p];
        xd *= depth;
        yd *= depth;
        const float* T = w + 9;
        float px = T[0] * xd + T[1] * yd + T[2]  * depth + T[3];
        float py = T[4] * xd + T[5] * yd + T[6]  * depth + T[7];
        float pz = T[8] * xd + T[9] * yd + T[10] * depth + T[11];
        pc_s[tid * 35 + 0] = px;
        pc_s[tid * 35 + 1] = py;
        pc_s[tid * 35 + 2] = pz;
    }
    __syncthreads();

    // ---- write phase: 15 masked copies of the tile, float4-coalesced ----
    for (int j = 0; j < J_; j++) {
        float4* out4 = (float4*)(out + ((size_t)(j * B_ + b) * HW_ + p0) * 35);
        const int* mj = m_s + j * TILE;
        for (int i4 = tid; i4 < TILE * 35 / 4; i4 += NTHREADS) {  // 1120 float4s
            int e  = i4 << 2;
            int pA = e / 35;            // compiler -> magic mul
            int r  = 35 - (e - pA * 35); // # components belonging to point pA (>=1)
            float4 v = *((const float4*)&pc_s[e]);
            int mA = mj[pA];
            int mB = (r < 4) ? mj[pA + 1] : mA;  // pA+1 <= 127 whenever r<4
            float4 o;
            o.x = mA ? v.x : 0.0f;
            o.y = ((r > 1) ? mA : mB) ? v.y : 0.0f;
            o.z = ((r > 2) ? mA : mB) ? v.z : 0.0f;
            o.w = ((r > 3) ? mA : mB) ? v.w : 0.0f;
            out4[i4] = o;
        }
    }
}

extern "C" void kernel_launch(void* const* d_in, const int* in_sizes, int n_in,
                              void* d_out, int out_size, void* d_ws, size_t ws_size,
                              hipStream_t stream) {
    const float* dep   = (const float*)d_in[0];  // pred_depth  [B,1,H,W]
    const int*   maskp = (const int*)  d_in[1];  // filter_mask [J,B,H,W]
    const float* K     = (const float*)d_in[2];  // K_matrix    [B,3,3]
    const float* M     = (const float*)d_in[3];  // M_matrix    [B,4,4]
    const float* diff  = (const float*)d_in[4];  // diff        [B,12]
    const float* trans = (const float*)d_in[5];  // trans_matrix[B,4,4]
    const float* feat  = (const float*)d_in[6];  // feature     [B,C,H,W]
    const int*   oW    = (const int*)  d_in[7];  // orig_W scalar
    const int*   oH    = (const int*)  d_in[8];  // orig_H scalar
    float* out = (float*)d_out;
    float* ws  = (float*)d_ws;

    setup_kernel<<<1, 64, 0, stream>>>(K, M, trans, ws);

    dim3 grid(HW_ / TILE, B_);   // 240 x 4 = 960 blocks
    points_kernel<<<grid, NTHREADS, 0, stream>>>(dep, maskp, feat, diff, ws, oW, oH, out);
}